// Round 10
// baseline (953.844 us; speedup 1.0000x reference)
//
#include <hip/hip_runtime.h>

typedef _Float16 f16;
typedef f16 half4 __attribute__((ext_vector_type(4)));
typedef f16 half8 __attribute__((ext_vector_type(8)));
typedef float f32x4 __attribute__((ext_vector_type(4)));

#define Pv 80000
#define G 7              // points per block (63 GEMM rows -> 4 M-tiles of 16, 1 garbage row)
#define AST 72           // LDS activation row stride in f16 (144B -> rows shift 4 banks; 2-way max = free)
#define NROW (G*10+1)    // shared zero-pad rows: [pad, s0..s8] x G + final pad = 71 rows
#define NGRP 11429       // ceil(80000/7)

// ws (f16) layout:
//   conv frags [L(4)][nt(4)][q(7)][lane(64)][8]   L: 0=ang1,1=ang2,2=nrm1,3=nrm2   (14336 f16/layer)
//   mlp  frags [nt(4)][q(4)][lane(64)][8]  at 57344
//   ang0 frag  [nt(4)][lane(64)][8]        at 65536  (K=9:  w'[t,c] = w[t,c] + sum_c' w[t,c'])
//   nrm0 frag  [nt(4)][lane(64)][8]        at 67584  (K=3:  w' = 2w)
// B-frag element: k = q*32 + (lane>>4)*8 + j -> W[k*64+n], n = nt*16+(lane&15)
// conv q==6: k=192..194 -> wsum[tap][n] (channel-sum trick as extra K-step); k>=195 -> 0.
//
// Block: 2 waves, one encoder each (wave0 ang -> A2[0], wave1 nrm -> A2[1]); sync; both
// waves split MLP + feats copy. Row mapping: point p slot i (i=0..10) at row p*10+i;
// pad rows (i=0,10) are SHARED between neighbors -> 71 rows, LDS/block 20448B.
// A row = 72 f16: cols 0..63 acts (MFMA reads bytes 0..127), col 64 rsb, cols 68..71 ib.
//
// OCCUPANCY MODEL (r2/r3/r5 counters): VGPR_Count reports ARCH regs only; the 64-reg
// MFMA accumulator tile rides on top in the unified file. r5: 128 arch + 64 acc = 192
// total -> 2 waves/SIMD -> 22% occ. r3: 64 arch budget -> 42% occ but massive spill
// (FETCH 98->723MB). This revision: __launch_bounds__(128,3) -> 170 total budget ->
// ~106 arch + 64 acc, expected zero/trivial spill and 3 waves/SIMD (~33% occ).

__global__ void setup_frags(const float* __restrict__ aw0, const float* __restrict__ nw0,
                            const float* __restrict__ aw1, const float* __restrict__ aw2,
                            const float* __restrict__ nw1, const float* __restrict__ nw2,
                            const float* __restrict__ mlp_w, f16* __restrict__ ws)
{
  int tid = blockIdx.x*blockDim.x + threadIdx.x;   // 8704 threads
  if (tid < 7168){
    int L    = tid / 1792;
    int rem  = tid % 1792;           // nt*448 + q*64 + lane
    int q    = (rem % 448) / 64;
    int lane = rem % 64;
    int nt   = rem / 448;
    const float* W = (L==0)?aw1:(L==1)?aw2:(L==2)?nw1:nw2;
    int n = nt*16 + (lane & 15);
    f16 o8[8];
    #pragma unroll
    for (int j=0;j<8;j++){
      int k = q*32 + (lane>>4)*8 + j;
      float v = 0.f;
      if (k < 192) v = W[k*64 + n];
      else if (k < 195){ int tap = k-192; float s=0.f;
        for (int c=0;c<64;c++) s += W[(tap*64+c)*64 + n]; v = s; }
      o8[j] = (f16)v;
    }
    *(half8*)(ws + (size_t)tid*8) = *(half8*)o8;
  } else if (tid < 8192){
    int t2 = tid - 7168;             // nt*256 + q*64 + lane
    int lane = t2 % 64;
    int q    = (t2 / 64) % 4;
    int nt   = t2 / 256;
    int n = nt*16 + (lane & 15);
    f16 o8[8];
    #pragma unroll
    for (int j=0;j<8;j++){
      int k = q*32 + (lane>>4)*8 + j;      // < 128
      o8[j] = (f16)mlp_w[k*64 + n];
    }
    *(half8*)(ws + 57344 + (size_t)t2*8) = *(half8*)o8;
  } else if (tid < 8704){
    int t3   = tid - 8192;           // [0,512): 256 ang0 then 256 nrm0
    int lane = t3 & 63;
    int nt   = (t3 >> 6) & 3;
    bool isang = t3 < 256;
    int n  = nt*16 + (lane & 15);
    int qd = lane >> 4;
    f16 o8[8];
    #pragma unroll
    for (int j=0;j<8;j++){
      int k = qd*8 + j;
      float v = 0.f;
      if (isang){
        if (k < 9){ int tap = k/3, c = k%3;
          float s3 = aw0[(tap*3+0)*64+n] + aw0[(tap*3+1)*64+n] + aw0[(tap*3+2)*64+n];
          v = aw0[(tap*3+c)*64+n] + s3; }
      } else {
        if (k < 3) v = 2.f * nw0[k*64+n];
      }
      o8[j] = (f16)v;
    }
    *(half8*)(ws + (isang ? 65536 : 67584) + ((size_t)(nt*64+lane))*8) = *(half8*)o8;
  }
}

// ---- layer 0 via MFMA (one K-step). A-frag gathered from ib cols (68..71); relu, store
// acts + rowsum->col64, carry C-fragment out as conv1's residual base.
template<bool IS_ANG>
__device__ __forceinline__ void layer0_mfma(const f16* __restrict__ frag,
    const float* __restrict__ bias, f16* A, int lane, half4 (&cres)[4][4])
{
  const int lo = lane & 15, qd = lane >> 4;
  float bn[4];
  #pragma unroll
  for (int nt=0;nt<4;nt++) bn[nt] = bias[nt*16 + lo];
  f32x4 acc[4][4];
  #pragma unroll
  for (int t=0;t<4;t++)
    #pragma unroll
    for (int nt=0;nt<4;nt++) acc[t][nt] = (f32x4){bn[nt],bn[nt],bn[nt],bn[nt]};

  half8 bv[4];
  #pragma unroll
  for (int nt=0;nt<4;nt++) bv[nt] = *(const half8*)(frag + ((nt*64+lane))*8);

  const f16 Z = (f16)0;
  #pragma unroll
  for (int t=0;t<4;t++){
    int m = t*16 + lo; if (m > 62) m = 62;
    int p = m/9, s = m - 9*p;
    const f16* ibp = A + (p*10 + s)*AST + 68;
    half4 h0 = *(const half4*)(ibp);
    half4 h1 = *(const half4*)(ibp + AST);
    half4 h2 = *(const half4*)(ibp + 2*AST);
    half8 av = (half8){Z,Z,Z,Z,Z,Z,Z,Z};
    if (IS_ANG){
      if (qd == 0)      av = (half8){h0[1],h0[2],h0[3],h1[1],h1[2],h1[3],h2[1],h2[2]};
      else if (qd == 1) av = (half8){h2[3],Z,Z,Z,Z,Z,Z,Z};
    } else {
      if (qd == 0)      av = (half8){h0[0],h1[0],h2[0],Z,Z,Z,Z,Z};
    }
    #pragma unroll
    for (int nt=0;nt<4;nt++)
      acc[t][nt] = __builtin_amdgcn_mfma_f32_16x16x32_f16(av, bv[nt], acc[t][nt], 0, 0, 0);
  }
  // epilogue: relu + store acts + rowsum + carry out (no residual at layer 0)
  #pragma unroll
  for (int t=0;t<4;t++){
    #pragma unroll
    for (int r=0;r<4;r++){
      int mr = t*16 + qd*4 + r;
      int mc = mr > 62 ? 62 : mr;
      int pr = mc/9, sr = mc - 9*pr;
      bool vld = (mr < 63);
      f16* rowA = A + (pr*10 + 1 + sr)*AST;
      float tmp = 0.f;
      #pragma unroll
      for (int nt=0;nt<4;nt++){
        float v = fmaxf(acc[t][nt][r], 0.f);
        cres[t][nt][r] = (f16)v; tmp += v;
      }
      tmp += __shfl_xor(tmp, 1); tmp += __shfl_xor(tmp, 2);
      tmp += __shfl_xor(tmp, 4); tmp += __shfl_xor(tmp, 8);
      if (vld){
        #pragma unroll
        for (int nt=0;nt<4;nt++) rowA[nt*16 + lo] = cres[t][nt][r];
        if (lo == 0) rowA[64] = (f16)tmp;
      }
    }
  }
}

// ---- conv layer via MFMA, in-place in A. Residual register-carried (cres).
template<bool WRITE_RS, bool CARRY_OUT>
__device__ __forceinline__ void conv_layer(const f16* __restrict__ frag,
    const float* __restrict__ bias, f16* A, int lane, half4 (&cres)[4][4])
{
  const int lo = lane & 15, qd = lane >> 4;
  float bn[4];
  #pragma unroll
  for (int nt=0;nt<4;nt++) bn[nt] = bias[nt*16 + lo];
  f32x4 acc[4][4];
  #pragma unroll
  for (int t=0;t<4;t++)
    #pragma unroll
    for (int nt=0;nt<4;nt++) acc[t][nt] = (f32x4){bn[nt],bn[nt],bn[nt],bn[nt]};

  int abase[4];
  #pragma unroll
  for (int t=0;t<4;t++){
    int m = t*16 + lo; if (m > 62) m = 62;      // row 63 is garbage (clamped, masked at store)
    int p = m/9, s = m - 9*p;
    abase[t] = ((p*10 + s)*AST)*2 + qd*16;      // byte addr; +tap*144 +(q&1)*64 are immediates
  }
  #pragma unroll
  for (int q=0;q<7;q++){
    half8 bv[4];
    #pragma unroll
    for (int nt=0;nt<4;nt++)
      bv[nt] = *(const half8*)(frag + ((nt*7 + q)*64 + lane)*8);
    #pragma unroll
    for (int t=0;t<4;t++){
      half8 av;
      if (q < 6){
        av = *(const half8*)((const char*)A + abase[t] + (q>>1)*(AST*2) + (q&1)*64);
      } else {
        // rsb col 64 of base row: f16 index = (abase>>1) - qd*8 + 64 (derived, no rbase array)
        const f16* rp = A + ((abase[t] >> 1) - qd*8 + 64);  // j=0..2 -> rs[s-1..s+1]
        av = (half8){rp[0], rp[AST], rp[2*AST], (f16)0, (f16)0, (f16)0, (f16)0, (f16)0};
      }
      #pragma unroll
      for (int nt=0;nt<4;nt++)
        acc[t][nt] = __builtin_amdgcn_mfma_f32_16x16x32_f16(av, bv[nt], acc[t][nt], 0, 0, 0);
    }
  }
  // epilogue: residual + relu + rowsum + store
  #pragma unroll
  for (int t=0;t<4;t++){
    #pragma unroll
    for (int r=0;r<4;r++){
      int mr = t*16 + qd*4 + r;
      int mc = mr > 62 ? 62 : mr;
      int pr = mc/9, sr = mc - 9*pr;
      bool vld = (mr < 63);
      f16* rowA = A + (pr*10 + 1 + sr)*AST;
      float tmp = 0.f, rnew[4];
      #pragma unroll
      for (int nt=0;nt<4;nt++){
        float rold = (float)cres[t][nt][r];
        float v = fmaxf(acc[t][nt][r], 0.f) + rold;
        rnew[nt] = v; tmp += v;
        if (CARRY_OUT) cres[t][nt][r] = (f16)v;
      }
      if (WRITE_RS){
        tmp += __shfl_xor(tmp, 1); tmp += __shfl_xor(tmp, 2);
        tmp += __shfl_xor(tmp, 4); tmp += __shfl_xor(tmp, 8);
      }
      if (vld){
        #pragma unroll
        for (int nt=0;nt<4;nt++) rowA[nt*16 + lo] = (f16)rnew[nt];
        if (WRITE_RS && lo == 0) rowA[64] = (f16)tmp;
      }
    }
  }
}

// ---- MLP: each wave does 2 of the 4 M-tiles. nrm_e in An (q<2), ang_e in Aa (q>=2).
__device__ __forceinline__ void mlp_out(const f16* __restrict__ frag,
    const float* __restrict__ mb, const f16* __restrict__ An, const f16* __restrict__ Aa,
    int lane, int wid, long pbase, float* __restrict__ out)
{
  const int lo = lane & 15, qd = lane >> 4;
  float bn[4];
  #pragma unroll
  for (int nt=0;nt<4;nt++) bn[nt] = mb[nt*16 + lo];
  f32x4 acc[2][4];
  #pragma unroll
  for (int tt=0;tt<2;tt++)
    #pragma unroll
    for (int nt=0;nt<4;nt++) acc[tt][nt] = (f32x4){bn[nt],bn[nt],bn[nt],bn[nt]};

  int aA[2];
  #pragma unroll
  for (int tt=0;tt<2;tt++){
    int m = (wid*2+tt)*16 + lo; if (m > 62) m = 62;
    int p = m/9, s = m - 9*p;
    aA[tt] = ((p*10 + 1 + s)*AST)*2 + qd*16;
  }
  #pragma unroll
  for (int q=0;q<4;q++){
    half8 bv[4];
    #pragma unroll
    for (int nt=0;nt<4;nt++)
      bv[nt] = *(const half8*)(frag + ((nt*4 + q)*64 + lane)*8);
    #pragma unroll
    for (int tt=0;tt<2;tt++){
      half8 av = (q < 2)
        ? *(const half8*)((const char*)An + aA[tt] + q*64)
        : *(const half8*)((const char*)Aa + aA[tt] + (q-2)*64);
      #pragma unroll
      for (int nt=0;nt<4;nt++)
        acc[tt][nt] = __builtin_amdgcn_mfma_f32_16x16x32_f16(av, bv[nt], acc[tt][nt], 0, 0, 0);
    }
  }
  #pragma unroll
  for (int tt=0;tt<2;tt++){
    #pragma unroll
    for (int r=0;r<4;r++){
      int mr = (wid*2+tt)*16 + qd*4 + r;
      int mc = mr > 62 ? 62 : mr;
      int pr = mc/9, sr = mc - 9*pr;
      long pg = pbase + pr;
      if (mr < 63 && pg < Pv){
        float* op = out + ((long)(pg*9 + sr))*128 + lo;
        #pragma unroll
        for (int nt=0;nt<4;nt++) op[nt*16] = fmaxf(acc[tt][nt][r], 0.f);
      }
    }
  }
}

__global__ __launch_bounds__(128, 3) void locse_main(
    const float* __restrict__ pc, const float* __restrict__ feats,
    const float* __restrict__ nb0, const float* __restrict__ nb1,
    const float* __restrict__ nb2, const float* __restrict__ ab0,
    const float* __restrict__ ab1, const float* __restrict__ ab2,
    const float* __restrict__ mb,  const f16* __restrict__ frag,
    float* __restrict__ out)
{
  __shared__ __align__(16) f16 A2[2][NROW*AST];  // 2 x 10224 B = 20448 B
  const int tid  = threadIdx.x;
  const int wid  = tid >> 6, lane = tid & 63;
  const long pbase = (long)blockIdx.x * G;
  f16* Aw = A2[wid];

  { // clear own A: pads + rsb col + ib cols must be zero
    const half8 z8 = {(f16)0,(f16)0,(f16)0,(f16)0,(f16)0,(f16)0,(f16)0,(f16)0};
    for (int i = lane; i < NROW*AST/8; i += 64) ((half8*)Aw)[i] = z8;
  }
  // derived features -> ib (own A cols 68..71); both waves compute redundantly
  if (lane < 63){
    int p = lane/9, s = lane - 9*p;
    long pg = pbase + p;
    if (pg < Pv){
      const float4 v  = *(const float4*)(pc + (pg*9 + s)*4);
      const float4 cu = *(const float4*)(pc + (pg*9)*4);
      float d0 = cu.x - v.x, d1 = cu.y - v.y;
      float n2  = v.x*v.x + v.y*v.y;                        float nrm = n2  > 0.f ? sqrtf(n2)  : 0.f;
      float dn2 = d0*d0 + d1*d1;                            float dn  = dn2 > 0.f ? sqrtf(dn2) : 0.f;
      float cn2 = cu.x*cu.x + cu.y*cu.y + cu.z*cu.z + cu.w*cu.w;
      float cn  = cn2 > 0.f ? sqrtf(cn2) : 0.f;
      float ang = 1.f - fabsf((d0*cu.z + d1*cu.w) / (dn*cn + 1e-8f));
      f16* ip = Aw + (p*10 + 1 + s)*AST + 68;
      ip[0]=(f16)d0; ip[1]=(f16)d1; ip[2]=(f16)nrm; ip[3]=(f16)ang;
    }
  }
  // wave 0: ang encoder -> A2[0];  wave 1: nrm encoder -> A2[1]
  half4 cres[4][4];
  if (wid == 0){
    layer0_mfma<true >(frag + 65536, ab0, Aw, lane, cres);
    conv_layer<true ,true >(frag + 0*14336, ab1, Aw, lane, cres);
    conv_layer<false,false>(frag + 1*14336, ab2, Aw, lane, cres);
  } else {
    layer0_mfma<false>(frag + 67584, nb0, Aw, lane, cres);
    conv_layer<true ,true >(frag + 2*14336, nb1, Aw, lane, cres);
    conv_layer<false,false>(frag + 3*14336, nb2, Aw, lane, cres);
  }
  __syncthreads();
  mlp_out(frag + 57344, mb, A2[1], A2[0], lane, wid, pbase, out);

  // feats passthrough (float4, fully coalesced; split across both waves)
  {
    const float4* ff = (const float4*)feats + pbase*144;
    float4* op = (float4*)out;
    #pragma unroll 1
    for (int i=0;i<8;i++){
      int idx = i*128 + tid;                 // float4 units: 7*9*16 = 1008
      if (idx < G*9*16){
        int ps = idx >> 4, c4 = idx & 15;
        long pg = pbase + ps/9;
        if (pg < Pv)
          op[(pbase*9 + (long)ps)*32 + 16 + c4] = ff[(long)ps*16 + c4];
      }
    }
  }
}

extern "C" void kernel_launch(void* const* d_in, const int* in_sizes, int n_in,
                              void* d_out, int out_size, void* d_ws, size_t ws_size,
                              hipStream_t stream)
{
  const float* pc    = (const float*)d_in[0];
  const float* feats = (const float*)d_in[1];
  const float* nw0=(const float*)d_in[14]; const float* nb0=(const float*)d_in[15];
  const float* nw1=(const float*)d_in[16]; const float* nb1=(const float*)d_in[17];
  const float* nw2=(const float*)d_in[18]; const float* nb2=(const float*)d_in[19];
  const float* aw0=(const float*)d_in[20]; const float* ab0=(const float*)d_in[21];
  const float* aw1=(const float*)d_in[22]; const float* ab1=(const float*)d_in[23];
  const float* aw2=(const float*)d_in[24]; const float* ab2=(const float*)d_in[25];
  const float* mw =(const float*)d_in[26]; const float* mb =(const float*)d_in[27];
  f16* ws  = (f16*)d_ws;
  float* out = (float*)d_out;

  setup_frags<<<34, 256, 0, stream>>>(aw0, nw0, aw1, aw2, nw1, nw2, mw, ws);
  locse_main<<<NGRP, 128, 0, stream>>>(pc, feats, nb0, nb1, nb2,
                                       ab0, ab1, ab2, mb, ws, out);
}

// Round 11
// 821.295 us; speedup vs baseline: 1.1614x; 1.1614x over previous
//
#include <hip/hip_runtime.h>

typedef _Float16 f16;
typedef f16 half4 __attribute__((ext_vector_type(4)));
typedef f16 half8 __attribute__((ext_vector_type(8)));
typedef float f32x4 __attribute__((ext_vector_type(4)));

#define Pv 80000
#define G 7              // points per block (63 GEMM rows -> 4 M-tiles of 16, 1 garbage row)
#define AST 72           // LDS activation row stride in f16 (144B -> rows shift 4 banks; 2-way max = free)
#define NROW (G*10+1)    // shared zero-pad rows: [pad, s0..s8] x G + final pad = 71 rows
#define NGRP 11429       // ceil(80000/7)

// ws (f16) layout:
//   conv frags [L(4)][nt(4)][q(7)][lane(64)][8]   L: 0=ang1,1=ang2,2=nrm1,3=nrm2   (14336 f16/layer)
//   mlp  frags [nt(4)][q(4)][lane(64)][8]  at 57344
//   ang0 frag  [nt(4)][lane(64)][8]        at 65536  (K=9:  w'[t,c] = w[t,c] + sum_c' w[t,c'])
//   nrm0 frag  [nt(4)][lane(64)][8]        at 67584  (K=3:  w' = 2w)
// B-frag element: k = q*32 + (lane>>4)*8 + j -> W[k*64+n], n = nt*16+(lane&15)
// conv q==6: k=192..194 -> wsum[tap][n] (channel-sum trick as extra K-step); k>=195 -> 0.
//
// Block (this revision): 4 waves. wave wid: enc=wid>>1 (0=ang->A2[0], 1=nrm->A2[1]),
// h=wid&1 (M-half: t = 2h..2h+1, rows m = 32h..32h+31). Each wave: acc[2][4] (32 regs)
// instead of acc[4][4] (64) -> total ~(arch ~90)+32 fits __launch_bounds__(256,4)
// = 4 waves/SIMD. The conv stencil crosses the half boundary (half0 epilogue writes
// row 35; half1 MFMA reads it), so each conv = [MFMA reads] barrier [epilogue writes],
// with call-site barriers between layers. All barriers uniformly executed: conv is
// called once with per-wave frag/bias pointers (no barrier inside divergent branches).
//
// OCCUPANCY MODEL (r2/r3/r5/r10 counters): VGPR_Count reports ARCH regs only; the MFMA
// acc tile rides on top in the unified file. r5: 128 arch + 64 acc = 192 -> 2 w/SIMD,
// 22% occ. r10 (128,3): occ rose to 32% as modeled BUT compiler squeezed arch to 84
// and spilled (FETCH 108->478MB, WRITE 380->1075MB, dur 338->549): live set ~179 regs
// doesn't fit 170. Hence this structural acc-halving instead of knob-turning.

__global__ void setup_frags(const float* __restrict__ aw0, const float* __restrict__ nw0,
                            const float* __restrict__ aw1, const float* __restrict__ aw2,
                            const float* __restrict__ nw1, const float* __restrict__ nw2,
                            const float* __restrict__ mlp_w, f16* __restrict__ ws)
{
  int tid = blockIdx.x*blockDim.x + threadIdx.x;   // 8704 threads
  if (tid < 7168){
    int L    = tid / 1792;
    int rem  = tid % 1792;           // nt*448 + q*64 + lane
    int q    = (rem % 448) / 64;
    int lane = rem % 64;
    int nt   = rem / 448;
    const float* W = (L==0)?aw1:(L==1)?aw2:(L==2)?nw1:nw2;
    int n = nt*16 + (lane & 15);
    f16 o8[8];
    #pragma unroll
    for (int j=0;j<8;j++){
      int k = q*32 + (lane>>4)*8 + j;
      float v = 0.f;
      if (k < 192) v = W[k*64 + n];
      else if (k < 195){ int tap = k-192; float s=0.f;
        for (int c=0;c<64;c++) s += W[(tap*64+c)*64 + n]; v = s; }
      o8[j] = (f16)v;
    }
    *(half8*)(ws + (size_t)tid*8) = *(half8*)o8;
  } else if (tid < 8192){
    int t2 = tid - 7168;             // nt*256 + q*64 + lane
    int lane = t2 % 64;
    int q    = (t2 / 64) % 4;
    int nt   = t2 / 256;
    int n = nt*16 + (lane & 15);
    f16 o8[8];
    #pragma unroll
    for (int j=0;j<8;j++){
      int k = q*32 + (lane>>4)*8 + j;      // < 128
      o8[j] = (f16)mlp_w[k*64 + n];
    }
    *(half8*)(ws + 57344 + (size_t)t2*8) = *(half8*)o8;
  } else if (tid < 8704){
    int t3   = tid - 8192;           // [0,512): 256 ang0 then 256 nrm0
    int lane = t3 & 63;
    int nt   = (t3 >> 6) & 3;
    bool isang = t3 < 256;
    int n  = nt*16 + (lane & 15);
    int qd = lane >> 4;
    f16 o8[8];
    #pragma unroll
    for (int j=0;j<8;j++){
      int k = qd*8 + j;
      float v = 0.f;
      if (isang){
        if (k < 9){ int tap = k/3, c = k%3;
          float s3 = aw0[(tap*3+0)*64+n] + aw0[(tap*3+1)*64+n] + aw0[(tap*3+2)*64+n];
          v = aw0[(tap*3+c)*64+n] + s3; }
      } else {
        if (k < 3) v = 2.f * nw0[k*64+n];
      }
      o8[j] = (f16)v;
    }
    *(half8*)(ws + (isang ? 65536 : 67584) + ((size_t)(nt*64+lane))*8) = *(half8*)o8;
  }
}

// ---- layer 0 via MFMA (one K-step), HALF of the M-tiles (t = 2h..2h+1).
// Reads only ib cols (68..71) -> no cross-wave hazard; no internal barrier needed.
template<bool IS_ANG>
__device__ __forceinline__ void layer0_mfma(const f16* __restrict__ frag,
    const float* __restrict__ bias, f16* A, int lane, int h, half4 (&cres)[2][4])
{
  const int lo = lane & 15, qd = lane >> 4;
  float bn[4];
  #pragma unroll
  for (int nt=0;nt<4;nt++) bn[nt] = bias[nt*16 + lo];
  f32x4 acc[2][4];
  #pragma unroll
  for (int tt=0;tt<2;tt++)
    #pragma unroll
    for (int nt=0;nt<4;nt++) acc[tt][nt] = (f32x4){bn[nt],bn[nt],bn[nt],bn[nt]};

  half8 bv[4];
  #pragma unroll
  for (int nt=0;nt<4;nt++) bv[nt] = *(const half8*)(frag + ((nt*64+lane))*8);

  const f16 Z = (f16)0;
  #pragma unroll
  for (int tt=0;tt<2;tt++){
    int m = (2*h+tt)*16 + lo; if (m > 62) m = 62;
    int p = m/9, s = m - 9*p;
    const f16* ibp = A + (p*10 + s)*AST + 68;
    half4 h0 = *(const half4*)(ibp);
    half4 h1 = *(const half4*)(ibp + AST);
    half4 h2 = *(const half4*)(ibp + 2*AST);
    half8 av = (half8){Z,Z,Z,Z,Z,Z,Z,Z};
    if (IS_ANG){
      if (qd == 0)      av = (half8){h0[1],h0[2],h0[3],h1[1],h1[2],h1[3],h2[1],h2[2]};
      else if (qd == 1) av = (half8){h2[3],Z,Z,Z,Z,Z,Z,Z};
    } else {
      if (qd == 0)      av = (half8){h0[0],h1[0],h2[0],Z,Z,Z,Z,Z};
    }
    #pragma unroll
    for (int nt=0;nt<4;nt++)
      acc[tt][nt] = __builtin_amdgcn_mfma_f32_16x16x32_f16(av, bv[nt], acc[tt][nt], 0, 0, 0);
  }
  // epilogue: relu + store acts + rowsum + carry out (no residual at layer 0)
  #pragma unroll
  for (int tt=0;tt<2;tt++){
    #pragma unroll
    for (int r=0;r<4;r++){
      int mr = (2*h+tt)*16 + qd*4 + r;
      int mc = mr > 62 ? 62 : mr;
      int pr = mc/9, sr = mc - 9*pr;
      bool vld = (mr < 63);
      f16* rowA = A + (pr*10 + 1 + sr)*AST;
      float tmp = 0.f;
      #pragma unroll
      for (int nt=0;nt<4;nt++){
        float v = fmaxf(acc[tt][nt][r], 0.f);
        cres[tt][nt][r] = (f16)v; tmp += v;
      }
      tmp += __shfl_xor(tmp, 1); tmp += __shfl_xor(tmp, 2);
      tmp += __shfl_xor(tmp, 4); tmp += __shfl_xor(tmp, 8);
      if (vld){
        #pragma unroll
        for (int nt=0;nt<4;nt++) rowA[nt*16 + lo] = cres[tt][nt][r];
        if (lo == 0) rowA[64] = (f16)tmp;
      }
    }
  }
}

// ---- conv layer via MFMA, in-place in A, HALF of the M-tiles. Residual in cres.
// Internal barrier between MFMA reads and epilogue writes: the stencil reads cross the
// half boundary (e.g. half1 m=32 reads row 35, written by half0 epilogue). MUST be
// called uniformly by all 4 waves (per-wave frag/bias pointers, no divergent call site).
template<bool WRITE_RS, bool CARRY_OUT>
__device__ __forceinline__ void conv_layer(const f16* __restrict__ frag,
    const float* __restrict__ bias, f16* A, int lane, int h, half4 (&cres)[2][4])
{
  const int lo = lane & 15, qd = lane >> 4;
  float bn[4];
  #pragma unroll
  for (int nt=0;nt<4;nt++) bn[nt] = bias[nt*16 + lo];
  f32x4 acc[2][4];
  #pragma unroll
  for (int tt=0;tt<2;tt++)
    #pragma unroll
    for (int nt=0;nt<4;nt++) acc[tt][nt] = (f32x4){bn[nt],bn[nt],bn[nt],bn[nt]};

  int abase[2];
  #pragma unroll
  for (int tt=0;tt<2;tt++){
    int m = (2*h+tt)*16 + lo; if (m > 62) m = 62;   // row 63 is garbage (masked at store)
    int p = m/9, s = m - 9*p;
    abase[tt] = ((p*10 + s)*AST)*2 + qd*16;         // byte addr; +tap*144 +(q&1)*64 imm
  }
  #pragma unroll
  for (int q=0;q<7;q++){
    half8 bv[4];
    #pragma unroll
    for (int nt=0;nt<4;nt++)
      bv[nt] = *(const half8*)(frag + ((nt*7 + q)*64 + lane)*8);
    #pragma unroll
    for (int tt=0;tt<2;tt++){
      half8 av;
      if (q < 6){
        av = *(const half8*)((const char*)A + abase[tt] + (q>>1)*(AST*2) + (q&1)*64);
      } else {
        // rsb col 64 of base row: f16 index = (abase>>1) - qd*8 + 64
        const f16* rp = A + ((abase[tt] >> 1) - qd*8 + 64);  // j=0..2 -> rs[s-1..s+1]
        av = (half8){rp[0], rp[AST], rp[2*AST], (f16)0, (f16)0, (f16)0, (f16)0, (f16)0};
      }
      #pragma unroll
      for (int nt=0;nt<4;nt++)
        acc[tt][nt] = __builtin_amdgcn_mfma_f32_16x16x32_f16(av, bv[nt], acc[tt][nt], 0, 0, 0);
    }
  }
  __syncthreads();   // all MFMA-phase reads complete before any half's epilogue writes
  // epilogue: residual + relu + rowsum + store (rows disjoint across halves)
  #pragma unroll
  for (int tt=0;tt<2;tt++){
    #pragma unroll
    for (int r=0;r<4;r++){
      int mr = (2*h+tt)*16 + qd*4 + r;
      int mc = mr > 62 ? 62 : mr;
      int pr = mc/9, sr = mc - 9*pr;
      bool vld = (mr < 63);
      f16* rowA = A + (pr*10 + 1 + sr)*AST;
      float tmp = 0.f, rnew[4];
      #pragma unroll
      for (int nt=0;nt<4;nt++){
        float rold = (float)cres[tt][nt][r];
        float v = fmaxf(acc[tt][nt][r], 0.f) + rold;
        rnew[nt] = v; tmp += v;
        if (CARRY_OUT) cres[tt][nt][r] = (f16)v;
      }
      if (WRITE_RS){
        tmp += __shfl_xor(tmp, 1); tmp += __shfl_xor(tmp, 2);
        tmp += __shfl_xor(tmp, 4); tmp += __shfl_xor(tmp, 8);
      }
      if (vld){
        #pragma unroll
        for (int nt=0;nt<4;nt++) rowA[nt*16 + lo] = (f16)rnew[nt];
        if (WRITE_RS && lo == 0) rowA[64] = (f16)tmp;
      }
    }
  }
}

// ---- MLP: each of 4 waves does 1 M-tile (t = wid). nrm_e in An (q<2), ang_e in Aa.
__device__ __forceinline__ void mlp_out(const f16* __restrict__ frag,
    const float* __restrict__ mb, const f16* __restrict__ An, const f16* __restrict__ Aa,
    int lane, int wid, long pbase, float* __restrict__ out)
{
  const int lo = lane & 15, qd = lane >> 4;
  float bn[4];
  #pragma unroll
  for (int nt=0;nt<4;nt++) bn[nt] = mb[nt*16 + lo];
  f32x4 acc[4];
  #pragma unroll
  for (int nt=0;nt<4;nt++) acc[nt] = (f32x4){bn[nt],bn[nt],bn[nt],bn[nt]};

  int m = wid*16 + lo; if (m > 62) m = 62;
  int p = m/9, s = m - 9*p;
  const int aA = ((p*10 + 1 + s)*AST)*2 + qd*16;
  #pragma unroll
  for (int q=0;q<4;q++){
    half8 bv[4];
    #pragma unroll
    for (int nt=0;nt<4;nt++)
      bv[nt] = *(const half8*)(frag + ((nt*4 + q)*64 + lane)*8);
    half8 av = (q < 2)
      ? *(const half8*)((const char*)An + aA + q*64)
      : *(const half8*)((const char*)Aa + aA + (q-2)*64);
    #pragma unroll
    for (int nt=0;nt<4;nt++)
      acc[nt] = __builtin_amdgcn_mfma_f32_16x16x32_f16(av, bv[nt], acc[nt], 0, 0, 0);
  }
  #pragma unroll
  for (int r=0;r<4;r++){
    int mr = wid*16 + qd*4 + r;
    int mc = mr > 62 ? 62 : mr;
    int pr = mc/9, sr = mc - 9*pr;
    long pg = pbase + pr;
    if (mr < 63 && pg < Pv){
      float* op = out + ((long)(pg*9 + sr))*128 + lo;
      #pragma unroll
      for (int nt=0;nt<4;nt++) op[nt*16] = fmaxf(acc[r >= 0 ? nt : nt][r], 0.f);
    }
  }
}

__global__ __launch_bounds__(256, 4) void locse_main(
    const float* __restrict__ pc, const float* __restrict__ feats,
    const float* __restrict__ nb0, const float* __restrict__ nb1,
    const float* __restrict__ nb2, const float* __restrict__ ab0,
    const float* __restrict__ ab1, const float* __restrict__ ab2,
    const float* __restrict__ mb,  const f16* __restrict__ frag,
    float* __restrict__ out)
{
  __shared__ __align__(16) f16 A2[2][NROW*AST];  // 2 x 10224 B = 20448 B
  const int tid  = threadIdx.x;
  const int wid  = tid >> 6, lane = tid & 63;
  const int enc  = wid >> 1, h = wid & 1;        // enc 0=ang->A2[0], 1=nrm->A2[1]
  const long pbase = (long)blockIdx.x * G;
  f16* Aw = A2[enc];

  { // clear both copies cooperatively (pads + rsb col + ib cols must be zero)
    const half8 z8 = {(f16)0,(f16)0,(f16)0,(f16)0,(f16)0,(f16)0,(f16)0,(f16)0};
    for (int i = tid; i < 2*NROW*AST/8; i += 256) ((half8*)A2)[i] = z8;
  }
  // derived features -> ib (cols 68..71 of both copies); wave 0 computes once
  if (tid < 63){
    int p = tid/9, s = tid - 9*p;
    long pg = pbase + p;
    if (pg < Pv){
      const float4 v  = *(const float4*)(pc + (pg*9 + s)*4);
      const float4 cu = *(const float4*)(pc + (pg*9)*4);
      float d0 = cu.x - v.x, d1 = cu.y - v.y;
      float n2  = v.x*v.x + v.y*v.y;                        float nrm = n2  > 0.f ? sqrtf(n2)  : 0.f;
      float dn2 = d0*d0 + d1*d1;                            float dn  = dn2 > 0.f ? sqrtf(dn2) : 0.f;
      float cn2 = cu.x*cu.x + cu.y*cu.y + cu.z*cu.z + cu.w*cu.w;
      float cn  = cn2 > 0.f ? sqrtf(cn2) : 0.f;
      float ang = 1.f - fabsf((d0*cu.z + d1*cu.w) / (dn*cn + 1e-8f));
      half4 hv = (half4){(f16)d0, (f16)d1, (f16)nrm, (f16)ang};
      int off = (p*10 + 1 + s)*AST + 68;                    // 8B-aligned
      *(half4*)(&A2[0][off]) = hv;
      *(half4*)(&A2[1][off]) = hv;
    }
  }
  __syncthreads();

  // per-wave weight pointers (uniform call sites so conv's internal barrier is uniform)
  const f16*  frag0 = frag + (enc ? 67584 : 65536);
  const float* b0   = enc ? nb0 : ab0;
  const f16*  fragL1= frag + (enc ? 2 : 0)*14336;
  const float* b1   = enc ? nb1 : ab1;
  const f16*  fragL2= frag + (enc ? 3 : 1)*14336;
  const float* b2   = enc ? nb2 : ab2;

  half4 cres[2][4];
  if (enc == 0) layer0_mfma<true >(frag0, b0, Aw, lane, h, cres);  // no barrier inside
  else          layer0_mfma<false>(frag0, b0, Aw, lane, h, cres);
  __syncthreads();
  conv_layer<true ,true >(fragL1, b1, Aw, lane, h, cres);
  __syncthreads();
  conv_layer<false,false>(fragL2, b2, Aw, lane, h, cres);
  __syncthreads();
  mlp_out(frag + 57344, mb, A2[1], A2[0], lane, wid, pbase, out);

  // feats passthrough (float4, fully coalesced; all 4 waves)
  {
    const float4* ff = (const float4*)feats + pbase*144;
    float4* op = (float4*)out;
    #pragma unroll 1
    for (int i=0;i<4;i++){
      int idx = i*256 + tid;                 // float4 units: 7*9*16 = 1008
      if (idx < G*9*16){
        int ps = idx >> 4, c4 = idx & 15;
        long pg = pbase + ps/9;
        if (pg < Pv)
          op[(pbase*9 + (long)ps)*32 + 16 + c4] = ff[(long)ps*16 + c4];
      }
    }
  }
}

extern "C" void kernel_launch(void* const* d_in, const int* in_sizes, int n_in,
                              void* d_out, int out_size, void* d_ws, size_t ws_size,
                              hipStream_t stream)
{
  const float* pc    = (const float*)d_in[0];
  const float* feats = (const float*)d_in[1];
  const float* nw0=(const float*)d_in[14]; const float* nb0=(const float*)d_in[15];
  const float* nw1=(const float*)d_in[16]; const float* nb1=(const float*)d_in[17];
  const float* nw2=(const float*)d_in[18]; const float* nb2=(const float*)d_in[19];
  const float* aw0=(const float*)d_in[20]; const float* ab0=(const float*)d_in[21];
  const float* aw1=(const float*)d_in[22]; const float* ab1=(const float*)d_in[23];
  const float* aw2=(const float*)d_in[24]; const float* ab2=(const float*)d_in[25];
  const float* mw =(const float*)d_in[26]; const float* mb =(const float*)d_in[27];
  f16* ws  = (f16*)d_ws;
  float* out = (float*)d_out;

  setup_frags<<<34, 256, 0, stream>>>(aw0, nw0, aw1, aw2, nw1, nw2, mw, ws);
  locse_main<<<NGRP, 256, 0, stream>>>(pc, feats, nb0, nb1, nb2,
                                       ab0, ab1, ab2, mb, ws, out);
}

// Round 14
// 704.651 us; speedup vs baseline: 1.3536x; 1.1655x over previous
//
#include <hip/hip_runtime.h>

typedef _Float16 f16;
typedef f16 half4 __attribute__((ext_vector_type(4)));
typedef f16 half8 __attribute__((ext_vector_type(8)));
typedef float f32x4 __attribute__((ext_vector_type(4)));

#define Pv 80000
#define G 7              // points per block (63 GEMM rows -> 4 M-tiles of 16, 1 garbage row)
#define AST 72           // LDS activation row stride in f16 (144B -> rows shift 4 banks; 2-way max = free)
#define NROW (G*10+1)    // shared zero-pad rows: [pad, s0..s8] x G + final pad = 71 rows
#define NGRP 11429       // ceil(80000/7)

// ws (f16) layout:
//   conv frags [L(4)][nt(4)][q(7)][lane(64)][8]   L: 0=ang1,1=ang2,2=nrm1,3=nrm2   (14336 f16/layer)
//   mlp  frags [nt(4)][q(4)][lane(64)][8]  at 57344
//   ang0 frag  [nt(4)][lane(64)][8]        at 65536  (K=9:  w'[t,c] = w[t,c] + sum_c' w[t,c'])
//   nrm0 frag  [nt(4)][lane(64)][8]        at 67584  (K=3:  w' = 2w)
// B-frag element: k = q*32 + (lane>>4)*8 + j -> W[k*64+n], n = nt*16+(lane&15)
// conv q==6: k=192..194 -> wsum[tap][n] (channel-sum trick as extra K-step); k>=195 -> 0.
//
// Block: 4 waves. wave wid: enc=wid>>1 (0=ang->A2[0], 1=nrm->A2[1]), h=wid&1 (M-half:
// t = 2h..2h+1). Each wave: acc[2][4] (32 regs). Conv stencil crosses the half boundary
// -> each conv = [MFMA reads] barrier [epilogue writes], uniform call sites.
//
// OCCUPANCY/SPILL LEDGER (r2..r11 counters; VGPR_Count = ARCH regs only, MFMA acc tile
// rides on top in the unified file):
//   r5  (128,2) 2-wave acc64: 128+64=192 total, clean,     occ 22%, 338us
//   r10 (128,3) 2-wave acc64:  84+64=148 total, SPILL,     occ 32%, 549us (live ~179)
//   r11 (256,4) 4-wave acc32:  64+32= 96 total, SPILL,     occ 45%, 420us (live ~110-120
//                              arch doesn't fit the 96-arch cap of a 128 budget)
// This revision: (256,3) -> 170 total budget -> arch cap ~138 >= live set -> ZERO SPILL
// at 3 waves/SIMD (~37% occ). Prediction: FETCH ~108MB WRITE ~380MB dur ~250-280us.

__global__ void setup_frags(const float* __restrict__ aw0, const float* __restrict__ nw0,
                            const float* __restrict__ aw1, const float* __restrict__ aw2,
                            const float* __restrict__ nw1, const float* __restrict__ nw2,
                            const float* __restrict__ mlp_w, f16* __restrict__ ws)
{
  int tid = blockIdx.x*blockDim.x + threadIdx.x;   // 8704 threads
  if (tid < 7168){
    int L    = tid / 1792;
    int rem  = tid % 1792;           // nt*448 + q*64 + lane
    int q    = (rem % 448) / 64;
    int lane = rem % 64;
    int nt   = rem / 448;
    const float* W = (L==0)?aw1:(L==1)?aw2:(L==2)?nw1:nw2;
    int n = nt*16 + (lane & 15);
    f16 o8[8];
    #pragma unroll
    for (int j=0;j<8;j++){
      int k = q*32 + (lane>>4)*8 + j;
      float v = 0.f;
      if (k < 192) v = W[k*64 + n];
      else if (k < 195){ int tap = k-192; float s=0.f;
        for (int c=0;c<64;c++) s += W[(tap*64+c)*64 + n]; v = s; }
      o8[j] = (f16)v;
    }
    *(half8*)(ws + (size_t)tid*8) = *(half8*)o8;
  } else if (tid < 8192){
    int t2 = tid - 7168;             // nt*256 + q*64 + lane
    int lane = t2 % 64;
    int q    = (t2 / 64) % 4;
    int nt   = t2 / 256;
    int n = nt*16 + (lane & 15);
    f16 o8[8];
    #pragma unroll
    for (int j=0;j<8;j++){
      int k = q*32 + (lane>>4)*8 + j;      // < 128
      o8[j] = (f16)mlp_w[k*64 + n];
    }
    *(half8*)(ws + 57344 + (size_t)t2*8) = *(half8*)o8;
  } else if (tid < 8704){
    int t3   = tid - 8192;           // [0,512): 256 ang0 then 256 nrm0
    int lane = t3 & 63;
    int nt   = (t3 >> 6) & 3;
    bool isang = t3 < 256;
    int n  = nt*16 + (lane & 15);
    int qd = lane >> 4;
    f16 o8[8];
    #pragma unroll
    for (int j=0;j<8;j++){
      int k = qd*8 + j;
      float v = 0.f;
      if (isang){
        if (k < 9){ int tap = k/3, c = k%3;
          float s3 = aw0[(tap*3+0)*64+n] + aw0[(tap*3+1)*64+n] + aw0[(tap*3+2)*64+n];
          v = aw0[(tap*3+c)*64+n] + s3; }
      } else {
        if (k < 3) v = 2.f * nw0[k*64+n];
      }
      o8[j] = (f16)v;
    }
    *(half8*)(ws + (isang ? 65536 : 67584) + ((size_t)(nt*64+lane))*8) = *(half8*)o8;
  }
}

// ---- layer 0 via MFMA (one K-step), HALF of the M-tiles (t = 2h..2h+1).
// Reads only ib cols (68..71) -> no cross-wave hazard; no internal barrier needed.
template<bool IS_ANG>
__device__ __forceinline__ void layer0_mfma(const f16* __restrict__ frag,
    const float* __restrict__ bias, f16* A, int lane, int h, half4 (&cres)[2][4])
{
  const int lo = lane & 15, qd = lane >> 4;
  float bn[4];
  #pragma unroll
  for (int nt=0;nt<4;nt++) bn[nt] = bias[nt*16 + lo];
  f32x4 acc[2][4];
  #pragma unroll
  for (int tt=0;tt<2;tt++)
    #pragma unroll
    for (int nt=0;nt<4;nt++) acc[tt][nt] = (f32x4){bn[nt],bn[nt],bn[nt],bn[nt]};

  half8 bv[4];
  #pragma unroll
  for (int nt=0;nt<4;nt++) bv[nt] = *(const half8*)(frag + ((nt*64+lane))*8);

  const f16 Z = (f16)0;
  #pragma unroll
  for (int tt=0;tt<2;tt++){
    int m = (2*h+tt)*16 + lo; if (m > 62) m = 62;
    int p = m/9, s = m - 9*p;
    const f16* ibp = A + (p*10 + s)*AST + 68;
    half4 h0 = *(const half4*)(ibp);
    half4 h1 = *(const half4*)(ibp + AST);
    half4 h2 = *(const half4*)(ibp + 2*AST);
    half8 av = (half8){Z,Z,Z,Z,Z,Z,Z,Z};
    if (IS_ANG){
      if (qd == 0)      av = (half8){h0[1],h0[2],h0[3],h1[1],h1[2],h1[3],h2[1],h2[2]};
      else if (qd == 1) av = (half8){h2[3],Z,Z,Z,Z,Z,Z,Z};
    } else {
      if (qd == 0)      av = (half8){h0[0],h1[0],h2[0],Z,Z,Z,Z,Z};
    }
    #pragma unroll
    for (int nt=0;nt<4;nt++)
      acc[tt][nt] = __builtin_amdgcn_mfma_f32_16x16x32_f16(av, bv[nt], acc[tt][nt], 0, 0, 0);
  }
  // epilogue: relu + store acts + rowsum + carry out (no residual at layer 0)
  #pragma unroll
  for (int tt=0;tt<2;tt++){
    #pragma unroll
    for (int r=0;r<4;r++){
      int mr = (2*h+tt)*16 + qd*4 + r;
      int mc = mr > 62 ? 62 : mr;
      int pr = mc/9, sr = mc - 9*pr;
      bool vld = (mr < 63);
      f16* rowA = A + (pr*10 + 1 + sr)*AST;
      float tmp = 0.f;
      #pragma unroll
      for (int nt=0;nt<4;nt++){
        float v = fmaxf(acc[tt][nt][r], 0.f);
        cres[tt][nt][r] = (f16)v; tmp += v;
      }
      tmp += __shfl_xor(tmp, 1); tmp += __shfl_xor(tmp, 2);
      tmp += __shfl_xor(tmp, 4); tmp += __shfl_xor(tmp, 8);
      if (vld){
        #pragma unroll
        for (int nt=0;nt<4;nt++) rowA[nt*16 + lo] = cres[tt][nt][r];
        if (lo == 0) rowA[64] = (f16)tmp;
      }
    }
  }
}

// ---- conv layer via MFMA, in-place in A, HALF of the M-tiles. Residual in cres.
// Internal barrier between MFMA reads and epilogue writes: the stencil reads cross the
// half boundary (e.g. half1 m=32 reads row 35, written by half0 epilogue). MUST be
// called uniformly by all 4 waves (per-wave frag/bias pointers, no divergent call site).
template<bool WRITE_RS, bool CARRY_OUT>
__device__ __forceinline__ void conv_layer(const f16* __restrict__ frag,
    const float* __restrict__ bias, f16* A, int lane, int h, half4 (&cres)[2][4])
{
  const int lo = lane & 15, qd = lane >> 4;
  float bn[4];
  #pragma unroll
  for (int nt=0;nt<4;nt++) bn[nt] = bias[nt*16 + lo];
  f32x4 acc[2][4];
  #pragma unroll
  for (int tt=0;tt<2;tt++)
    #pragma unroll
    for (int nt=0;nt<4;nt++) acc[tt][nt] = (f32x4){bn[nt],bn[nt],bn[nt],bn[nt]};

  int abase[2];
  #pragma unroll
  for (int tt=0;tt<2;tt++){
    int m = (2*h+tt)*16 + lo; if (m > 62) m = 62;   // row 63 is garbage (masked at store)
    int p = m/9, s = m - 9*p;
    abase[tt] = ((p*10 + s)*AST)*2 + qd*16;         // byte addr; +tap*144 +(q&1)*64 imm
  }
  #pragma unroll
  for (int q=0;q<7;q++){
    half8 bv[4];
    #pragma unroll
    for (int nt=0;nt<4;nt++)
      bv[nt] = *(const half8*)(frag + ((nt*7 + q)*64 + lane)*8);
    #pragma unroll
    for (int tt=0;tt<2;tt++){
      half8 av;
      if (q < 6){
        av = *(const half8*)((const char*)A + abase[tt] + (q>>1)*(AST*2) + (q&1)*64);
      } else {
        // rsb col 64 of base row: f16 index = (abase>>1) - qd*8 + 64
        const f16* rp = A + ((abase[tt] >> 1) - qd*8 + 64);  // j=0..2 -> rs[s-1..s+1]
        av = (half8){rp[0], rp[AST], rp[2*AST], (f16)0, (f16)0, (f16)0, (f16)0, (f16)0};
      }
      #pragma unroll
      for (int nt=0;nt<4;nt++)
        acc[tt][nt] = __builtin_amdgcn_mfma_f32_16x16x32_f16(av, bv[nt], acc[tt][nt], 0, 0, 0);
    }
  }
  __syncthreads();   // all MFMA-phase reads complete before any half's epilogue writes
  // epilogue: residual + relu + rowsum + store (rows disjoint across halves)
  #pragma unroll
  for (int tt=0;tt<2;tt++){
    #pragma unroll
    for (int r=0;r<4;r++){
      int mr = (2*h+tt)*16 + qd*4 + r;
      int mc = mr > 62 ? 62 : mr;
      int pr = mc/9, sr = mc - 9*pr;
      bool vld = (mr < 63);
      f16* rowA = A + (pr*10 + 1 + sr)*AST;
      float tmp = 0.f, rnew[4];
      #pragma unroll
      for (int nt=0;nt<4;nt++){
        float rold = (float)cres[tt][nt][r];
        float v = fmaxf(acc[tt][nt][r], 0.f) + rold;
        rnew[nt] = v; tmp += v;
        if (CARRY_OUT) cres[tt][nt][r] = (f16)v;
      }
      if (WRITE_RS){
        tmp += __shfl_xor(tmp, 1); tmp += __shfl_xor(tmp, 2);
        tmp += __shfl_xor(tmp, 4); tmp += __shfl_xor(tmp, 8);
      }
      if (vld){
        #pragma unroll
        for (int nt=0;nt<4;nt++) rowA[nt*16 + lo] = (f16)rnew[nt];
        if (WRITE_RS && lo == 0) rowA[64] = (f16)tmp;
      }
    }
  }
}

// ---- MLP: each of 4 waves does 1 M-tile (t = wid). nrm_e in An (q<2), ang_e in Aa.
__device__ __forceinline__ void mlp_out(const f16* __restrict__ frag,
    const float* __restrict__ mb, const f16* __restrict__ An, const f16* __restrict__ Aa,
    int lane, int wid, long pbase, float* __restrict__ out)
{
  const int lo = lane & 15, qd = lane >> 4;
  float bn[4];
  #pragma unroll
  for (int nt=0;nt<4;nt++) bn[nt] = mb[nt*16 + lo];
  f32x4 acc[4];
  #pragma unroll
  for (int nt=0;nt<4;nt++) acc[nt] = (f32x4){bn[nt],bn[nt],bn[nt],bn[nt]};

  int m = wid*16 + lo; if (m > 62) m = 62;
  int p = m/9, s = m - 9*p;
  const int aA = ((p*10 + 1 + s)*AST)*2 + qd*16;
  #pragma unroll
  for (int q=0;q<4;q++){
    half8 bv[4];
    #pragma unroll
    for (int nt=0;nt<4;nt++)
      bv[nt] = *(const half8*)(frag + ((nt*4 + q)*64 + lane)*8);
    half8 av = (q < 2)
      ? *(const half8*)((const char*)An + aA + q*64)
      : *(const half8*)((const char*)Aa + aA + (q-2)*64);
    #pragma unroll
    for (int nt=0;nt<4;nt++)
      acc[nt] = __builtin_amdgcn_mfma_f32_16x16x32_f16(av, bv[nt], acc[nt], 0, 0, 0);
  }
  #pragma unroll
  for (int r=0;r<4;r++){
    int mr = wid*16 + qd*4 + r;
    int mc = mr > 62 ? 62 : mr;
    int pr = mc/9, sr = mc - 9*pr;
    long pg = pbase + pr;
    if (mr < 63 && pg < Pv){
      float* op = out + ((long)(pg*9 + sr))*128 + lo;
      #pragma unroll
      for (int nt=0;nt<4;nt++) op[nt*16] = fmaxf(acc[nt][r], 0.f);
    }
  }
}

__global__ __launch_bounds__(256, 3) void locse_main(
    const float* __restrict__ pc, const float* __restrict__ feats,
    const float* __restrict__ nb0, const float* __restrict__ nb1,
    const float* __restrict__ nb2, const float* __restrict__ ab0,
    const float* __restrict__ ab1, const float* __restrict__ ab2,
    const float* __restrict__ mb,  const f16* __restrict__ frag,
    float* __restrict__ out)
{
  __shared__ __align__(16) f16 A2[2][NROW*AST];  // 2 x 10224 B = 20448 B
  const int tid  = threadIdx.x;
  const int wid  = tid >> 6, lane = tid & 63;
  const int enc  = wid >> 1, h = wid & 1;        // enc 0=ang->A2[0], 1=nrm->A2[1]
  const long pbase = (long)blockIdx.x * G;
  f16* Aw = A2[enc];

  { // clear both copies cooperatively (pads + rsb col + ib cols must be zero)
    const half8 z8 = {(f16)0,(f16)0,(f16)0,(f16)0,(f16)0,(f16)0,(f16)0,(f16)0};
    for (int i = tid; i < 2*NROW*AST/8; i += 256) ((half8*)A2)[i] = z8;
  }
  // derived features -> ib (cols 68..71 of both copies); wave 0 computes once
  if (tid < 63){
    int p = tid/9, s = tid - 9*p;
    long pg = pbase + p;
    if (pg < Pv){
      const float4 v  = *(const float4*)(pc + (pg*9 + s)*4);
      const float4 cu = *(const float4*)(pc + (pg*9)*4);
      float d0 = cu.x - v.x, d1 = cu.y - v.y;
      float n2  = v.x*v.x + v.y*v.y;                        float nrm = n2  > 0.f ? sqrtf(n2)  : 0.f;
      float dn2 = d0*d0 + d1*d1;                            float dn  = dn2 > 0.f ? sqrtf(dn2) : 0.f;
      float cn2 = cu.x*cu.x + cu.y*cu.y + cu.z*cu.z + cu.w*cu.w;
      float cn  = cn2 > 0.f ? sqrtf(cn2) : 0.f;
      float ang = 1.f - fabsf((d0*cu.z + d1*cu.w) / (dn*cn + 1e-8f));
      half4 hv = (half4){(f16)d0, (f16)d1, (f16)nrm, (f16)ang};
      int off = (p*10 + 1 + s)*AST + 68;                    // 8B-aligned
      *(half4*)(&A2[0][off]) = hv;
      *(half4*)(&A2[1][off]) = hv;
    }
  }
  __syncthreads();

  // per-wave weight pointers (uniform call sites so conv's internal barrier is uniform)
  const f16*  frag0 = frag + (enc ? 67584 : 65536);
  const float* b0   = enc ? nb0 : ab0;
  const f16*  fragL1= frag + (enc ? 2 : 0)*14336;
  const float* b1   = enc ? nb1 : ab1;
  const f16*  fragL2= frag + (enc ? 3 : 1)*14336;
  const float* b2   = enc ? nb2 : ab2;

  half4 cres[2][4];
  if (enc == 0) layer0_mfma<true >(frag0, b0, Aw, lane, h, cres);  // no barrier inside
  else          layer0_mfma<false>(frag0, b0, Aw, lane, h, cres);
  __syncthreads();
  conv_layer<true ,true >(fragL1, b1, Aw, lane, h, cres);
  __syncthreads();
  conv_layer<false,false>(fragL2, b2, Aw, lane, h, cres);
  __syncthreads();
  mlp_out(frag + 57344, mb, A2[1], A2[0], lane, wid, pbase, out);

  // feats passthrough (float4, fully coalesced; all 4 waves)
  {
    const float4* ff = (const float4*)feats + pbase*144;
    float4* op = (float4*)out;
    #pragma unroll 1
    for (int i=0;i<4;i++){
      int idx = i*256 + tid;                 // float4 units: 7*9*16 = 1008
      if (idx < G*9*16){
        int ps = idx >> 4, c4 = idx & 15;
        long pg = pbase + ps/9;
        if (pg < Pv)
          op[(pbase*9 + (long)ps)*32 + 16 + c4] = ff[(long)ps*16 + c4];
      }
    }
  }
}

extern "C" void kernel_launch(void* const* d_in, const int* in_sizes, int n_in,
                              void* d_out, int out_size, void* d_ws, size_t ws_size,
                              hipStream_t stream)
{
  const float* pc    = (const float*)d_in[0];
  const float* feats = (const float*)d_in[1];
  const float* nw0=(const float*)d_in[14]; const float* nb0=(const float*)d_in[15];
  const float* nw1=(const float*)d_in[16]; const float* nb1=(const float*)d_in[17];
  const float* nw2=(const float*)d_in[18]; const float* nb2=(const float*)d_in[19];
  const float* aw0=(const float*)d_in[20]; const float* ab0=(const float*)d_in[21];
  const float* aw1=(const float*)d_in[22]; const float* ab1=(const float*)d_in[23];
  const float* aw2=(const float*)d_in[24]; const float* ab2=(const float*)d_in[25];
  const float* mw =(const float*)d_in[26]; const float* mb =(const float*)d_in[27];
  f16* ws  = (f16*)d_ws;
  float* out = (float*)d_out;

  setup_frags<<<34, 256, 0, stream>>>(aw0, nw0, aw1, aw2, nw1, nw2, mw, ws);
  locse_main<<<NGRP, 256, 0, stream>>>(pc, feats, nb0, nb1, nb2,
                                       ab0, ab1, ab2, mb, ws, out);
}